// Round 2
// baseline (68.568 us; speedup 1.0000x reference)
//
#include <hip/hip_runtime.h>
#include <hip/hip_bf16.h>

#define NSTEPS 512
#define NINC   511   // number of increments (L-1)
#define SIGDIM 126   // 2+4+8+16+32+64

// Level-k block lives at offset (1<<k)-2, size 1<<k, for k=1..6.
// Same layout as the reference's concatenated output row.

// A = A (x) exp(dx), truncated at order 6, in place.
// Horner form: U_1 = dx/k; U_i = (A_{i-1} + U_{i-1}) (x) dx * 1/(k-i+1);
// C_k = A_k + U_k.  Verified by hand vs reference at k=2,3.
// Descending k => in-place safe (C_k reads only levels < k of old A).
__device__ __forceinline__ void mul_exp(float* A, float d0, float d1) {
  const float rinv[7] = {0.f, 1.f, 0.5f, (1.f/3.f), 0.25f, 0.2f, (1.f/6.f)};
  #pragma unroll
  for (int k = 6; k >= 1; --k) {
    float U[64];
    U[0] = d0 * rinv[k];
    U[1] = d1 * rinv[k];
    #pragma unroll
    for (int i = 2; i <= k; ++i) {
      const float e0 = d0 * rinv[k - i + 1];
      const float e1 = d1 * rinv[k - i + 1];
      const int po = (1 << (i - 1)) - 2;   // offset of level i-1
      float Un[64];
      #pragma unroll
      for (int j = 0; j < (1 << (i - 1)); ++j) {
        const float s = A[po + j] + U[j];
        Un[2 * j]     = s * e0;   // previous-index major, dx minor
        Un[2 * j + 1] = s * e1;
      }
      #pragma unroll
      for (int j = 0; j < (1 << i); ++j) U[j] = Un[j];
    }
    const int ko = (1 << k) - 2;
    #pragma unroll
    for (int j = 0; j < (1 << k); ++j) A[ko + j] += U[j];
  }
}

// A = A (x) B (Chen / truncated tensor-algebra product, level-0 == 1 implicit).
// C_k = A_k + B_k + sum_{i=1}^{k-1} A_i (x) B_{k-i}.  Descending k => in-place safe.
__device__ __forceinline__ void mul_chen(float* A, const float* B) {
  #pragma unroll
  for (int k = 6; k >= 1; --k) {
    const int ko = (1 << k) - 2;
    #pragma unroll
    for (int j = 0; j < (1 << k); ++j) {
      float c = A[ko + j] + B[ko + j];
      #pragma unroll
      for (int i = 1; i < k; ++i) {
        const int ai = (1 << i) - 2;
        const int bi = (1 << (k - i)) - 2;
        c += A[ai + (j >> (k - i))] * B[bi + (j & ((1 << (k - i)) - 1))];
      }
      A[ko + j] = c;
    }
  }
}

// grid 64 x block 64. Each block redundantly computes the batch-independent
// signature sig[126] (phase 1+2), then lane l writes row blockIdx*64+l:
// out[row, d] = x[row]^level(d) * sig[d].
__global__ __launch_bounds__(64, 1)
void Invert_sig_kernel(const float* __restrict__ x,
                       const float* __restrict__ W,
                       float* __restrict__ out) {
  const int lane = threadIdx.x;

  float A[SIGDIM];
  #pragma unroll
  for (int j = 0; j < SIGDIM; ++j) A[j] = 0.0f;  // identity element (level0==1)

  // ---- phase 1: each lane folds 8 consecutive increments t = lane*8+s ----
  // increment t: dx[c] = x * W[c*512 + t + 1]  (cumsum diff == W row), t in [0, 511)
  #pragma unroll 1
  for (int s = 0; s < 8; ++s) {
    const int t = lane * 8 + s;
    const bool valid = (t < NINC);
    const float d0 = valid ? W[t + 1] : 0.0f;
    const float d1 = valid ? W[NSTEPS + t + 1] : 0.0f;  // exp(0)=identity pad
    mul_exp(A, d0, d1);
  }

  // ---- phase 2: tree-reduce Chen product across 64 lanes (associative) ----
  // Lane 0's dependency cone only ever reads partners < 64 (verified); OOB
  // shuffle garbage in high lanes never propagates to lane 0.
  #pragma unroll 1
  for (int r = 0; r < 6; ++r) {
    const int bit = 1 << r;
    float Bv[SIGDIM];
    #pragma unroll
    for (int j = 0; j < SIGDIM; ++j) Bv[j] = __shfl_down(A[j], bit, 64);
    mul_chen(A, Bv);  // self (lower t, left) (x) partner (higher t, right)
  }

  __shared__ float sig[SIGDIM];
  if (lane == 0) {
    #pragma unroll
    for (int j = 0; j < SIGDIM; ++j) sig[j] = A[j];
  }
  __syncthreads();

  // ---- phase 3: one output row per lane ----
  const int row = blockIdx.x * 64 + lane;
  const float xr = x[row];
  float p[7];
  p[1] = xr;
  #pragma unroll
  for (int k = 2; k <= 6; ++k) p[k] = p[k - 1] * xr;

  float* orow = out + row * SIGDIM;   // 504 B apart -> 8 B aligned, use float2
  #pragma unroll
  for (int d = 0; d < SIGDIM; d += 2) {
    // level boundaries (2,6,14,30,62) are even => pair never straddles levels
    const int k = (d < 2) ? 1 : (d < 6) ? 2 : (d < 14) ? 3
                : (d < 30) ? 4 : (d < 62) ? 5 : 6;
    float2 v;
    v.x = sig[d] * p[k];
    v.y = sig[d + 1] * p[k];
    *reinterpret_cast<float2*>(orow + d) = v;
  }
}

extern "C" void kernel_launch(void* const* d_in, const int* in_sizes, int n_in,
                              void* d_out, int out_size, void* d_ws, size_t ws_size,
                              hipStream_t stream) {
  const float* x = (const float*)d_in[0];  // (4096,1) f32
  const float* W = (const float*)d_in[1];  // (1024,1) f32
  float* out = (float*)d_out;              // (4096,126) f32
  Invert_sig_kernel<<<dim3(64), dim3(64), 0, stream>>>(x, W, out);
}

// Round 3
// 67.788 us; speedup vs baseline: 1.0115x; 1.0115x over previous
//
#include <hip/hip_runtime.h>
#include <hip/hip_bf16.h>

#define NSTEPS 512
#define NINC   511   // number of increments (L-1)
#define SIGDIM 126   // 2+4+8+16+32+64

// Level-k block lives at offset (1<<k)-2, size 1<<k, for k=1..6.
// Same layout as the reference's concatenated output row.

// A = exp levels of dx (signature of a single linear segment), from scratch.
__device__ __forceinline__ void exp_levels(float* A, float d0, float d1) {
  const float rinv[7] = {0.f, 1.f, 0.5f, (1.f/3.f), 0.25f, 0.2f, (1.f/6.f)};
  A[0] = d0; A[1] = d1;
  #pragma unroll
  for (int k = 2; k <= 6; ++k) {
    const int po = (1 << (k - 1)) - 2, ko = (1 << k) - 2;
    const float e0 = d0 * rinv[k], e1 = d1 * rinv[k];
    #pragma unroll
    for (int j = 0; j < (1 << (k - 1)); ++j) {
      A[ko + 2 * j]     = A[po + j] * e0;
      A[ko + 2 * j + 1] = A[po + j] * e1;
    }
  }
}

// A = A (x) exp(dx), truncated at order 6, in place.
// Horner: U_1 = dx/k; U_i = (A_{i-1} + U_{i-1}) (x) dx * 1/(k-i+1); C_k = A_k + U_k.
// In-place U expansion: descending j writes U[2j],U[2j+1] after reading U[j]
// (2j > j for j>=1; j=0 reads U[0] first, U[1] already consumed at j=1).
// Descending k => A in-place safe (level k reads only levels < k of old A).
__device__ __forceinline__ void mul_exp(float* A, float d0, float d1) {
  const float rinv[7] = {0.f, 1.f, 0.5f, (1.f/3.f), 0.25f, 0.2f, (1.f/6.f)};
  #pragma unroll
  for (int k = 6; k >= 1; --k) {
    float U[64];                    // grows 2 -> 2^k in place
    U[0] = d0 * rinv[k];
    U[1] = d1 * rinv[k];
    #pragma unroll
    for (int i = 2; i <= k; ++i) {
      const float e0 = d0 * rinv[k - i + 1];
      const float e1 = d1 * rinv[k - i + 1];
      const int po = (1 << (i - 1)) - 2;   // offset of level i-1
      #pragma unroll
      for (int j = (1 << (i - 1)) - 1; j >= 0; --j) {
        const float s = A[po + j] + U[j];
        U[2 * j + 1] = s * e1;       // previous-index major, dx minor
        U[2 * j]     = s * e0;
      }
    }
    const int ko = (1 << k) - 2;
    #pragma unroll
    for (int j = 0; j < (1 << k); ++j) A[ko + j] += U[j];
  }
}

// grid 64 x block 64 (one wave). Each block redundantly computes the
// batch-independent signature sig[126], then lane l writes row blk*64+l:
// out[row, d] = x[row]^level(d) * sig[d].
__global__ __launch_bounds__(64, 1)
void Invert_sig_kernel(const float* __restrict__ x,
                       const float* __restrict__ W,
                       float* __restrict__ out) {
  const int lane = threadIdx.x;

  float A[SIGDIM];

  // ---- phase 1: lane folds 8 consecutive increments t = lane*8+s ----
  // increment t: dx[c] = W[c*512 + t + 1] (cumsum diff == W row), t in [0,511)
  {
    const int t0 = lane * 8;                  // t0 <= 504 < 511: always valid
    exp_levels(A, W[t0 + 1], W[NSTEPS + t0 + 1]);
  }
  #pragma unroll 1
  for (int s = 1; s < 8; ++s) {
    const int t = lane * 8 + s;
    const bool valid = (t < NINC);            // only lane 63, s==7 is padding
    const float d0 = valid ? W[t + 1] : 0.0f;
    const float d1 = valid ? W[NSTEPS + t + 1] : 0.0f;  // exp(0) = identity
    mul_exp(A, d0, d1);
  }

  // ---- phase 2: tree-reduce Chen product across 64 lanes (associative) ----
  // C_k = A_k + B_k + sum_{i=1}^{k-1} A_i (x) B_{k-i};  B = partner (higher t).
  // Only B levels 1..5 are materialized (Bv[62]); level-6 B is streamed one
  // shfl at a time and consumed immediately (each B6[j] is used exactly once).
  // Wave lockstep: all lanes shuffle old A[62+j] before any lane overwrites it.
  #pragma unroll 1
  for (int r = 0; r < 6; ++r) {
    const int bit = 1 << r;
    float Bv[62];
    #pragma unroll
    for (int j = 0; j < 62; ++j) Bv[j] = __shfl_down(A[j], bit, 64);
    // k = 6, streamed B6
    #pragma unroll
    for (int j = 0; j < 64; ++j) {
      const float b6 = __shfl_down(A[62 + j], bit, 64);
      float c = A[62 + j] + b6;
      #pragma unroll
      for (int i = 1; i < 6; ++i)
        c += A[(1 << i) - 2 + (j >> (6 - i))] *
             Bv[(1 << (6 - i)) - 2 + (j & ((1 << (6 - i)) - 1))];
      A[62 + j] = c;
    }
    // k = 5..1 from Bv (descending k => in-place safe)
    #pragma unroll
    for (int k = 5; k >= 1; --k) {
      const int ko = (1 << k) - 2;
      #pragma unroll
      for (int j = 0; j < (1 << k); ++j) {
        float c = A[ko + j] + Bv[ko + j];
        #pragma unroll
        for (int i = 1; i < k; ++i)
          c += A[(1 << i) - 2 + (j >> (k - i))] *
               Bv[(1 << (k - i)) - 2 + (j & ((1 << (k - i)) - 1))];
        A[ko + j] = c;
      }
    }
  }

  __shared__ float sig[SIGDIM];
  if (lane == 0) {
    #pragma unroll
    for (int j = 0; j < SIGDIM; ++j) sig[j] = A[j];
  }
  __syncthreads();

  // ---- phase 3: one output row per lane ----
  const int row = blockIdx.x * 64 + lane;
  const float xr = x[row];
  float p[7];
  p[1] = xr;
  #pragma unroll
  for (int k = 2; k <= 6; ++k) p[k] = p[k - 1] * xr;

  float* orow = out + row * SIGDIM;   // rows 504 B apart -> 8 B aligned: float2
  #pragma unroll
  for (int d = 0; d < SIGDIM; d += 2) {
    // level boundaries (2,6,14,30,62) are even => pair never straddles levels
    const int k = (d < 2) ? 1 : (d < 6) ? 2 : (d < 14) ? 3
                : (d < 30) ? 4 : (d < 62) ? 5 : 6;
    float2 v;
    v.x = sig[d] * p[k];
    v.y = sig[d + 1] * p[k];
    *reinterpret_cast<float2*>(orow + d) = v;
  }
}

extern "C" void kernel_launch(void* const* d_in, const int* in_sizes, int n_in,
                              void* d_out, int out_size, void* d_ws, size_t ws_size,
                              hipStream_t stream) {
  const float* x = (const float*)d_in[0];  // (4096,1) f32
  const float* W = (const float*)d_in[1];  // (1024,1) f32
  float* out = (float*)d_out;              // (4096,126) f32
  Invert_sig_kernel<<<dim3(64), dim3(64), 0, stream>>>(x, W, out);
}

// Round 4
// 66.638 us; speedup vs baseline: 1.0290x; 1.0172x over previous
//
#include <hip/hip_runtime.h>
#include <hip/hip_bf16.h>

#define NSTEPS 512
#define NINC   511   // number of increments (L-1)
#define SIGDIM 126   // 2+4+8+16+32+64

// Level-k block lives at offset (1<<k)-2, size 1<<k, for k=1..6.
// Same layout as the reference's concatenated output row.

// A = exp levels of dx (signature of a single linear segment), from scratch.
__device__ __forceinline__ void exp_levels(float* A, float d0, float d1) {
  const float rinv[7] = {0.f, 1.f, 0.5f, (1.f/3.f), 0.25f, 0.2f, (1.f/6.f)};
  A[0] = d0; A[1] = d1;
  #pragma unroll
  for (int k = 2; k <= 6; ++k) {
    const int po = (1 << (k - 1)) - 2, ko = (1 << k) - 2;
    const float e0 = d0 * rinv[k], e1 = d1 * rinv[k];
    #pragma unroll
    for (int j = 0; j < (1 << (k - 1)); ++j) {
      A[ko + 2 * j]     = A[po + j] * e0;
      A[ko + 2 * j + 1] = A[po + j] * e1;
    }
  }
}

// A = A (x) exp(dx), truncated at order 6, in place.
// Horner: U_1 = dx/k; U_i = (A_{i-1} + U_{i-1}) (x) dx * 1/(k-i+1); C_k = A_k + U_k.
// In-place U expansion: descending j writes U[2j],U[2j+1] after reading U[j].
// Descending k => A in-place safe. The 6 k-chains are mutually independent
// (k reads old levels < k, writes level k) -> good ILP for the scheduler.
__device__ __forceinline__ void mul_exp(float* A, float d0, float d1) {
  const float rinv[7] = {0.f, 1.f, 0.5f, (1.f/3.f), 0.25f, 0.2f, (1.f/6.f)};
  #pragma unroll
  for (int k = 6; k >= 1; --k) {
    float U[64];                    // grows 2 -> 2^k in place
    U[0] = d0 * rinv[k];
    U[1] = d1 * rinv[k];
    #pragma unroll
    for (int i = 2; i <= k; ++i) {
      const float e0 = d0 * rinv[k - i + 1];
      const float e1 = d1 * rinv[k - i + 1];
      const int po = (1 << (i - 1)) - 2;   // offset of level i-1
      #pragma unroll
      for (int j = (1 << (i - 1)) - 1; j >= 0; --j) {
        const float s = A[po + j] + U[j];
        U[2 * j + 1] = s * e1;       // previous-index major, dx minor
        U[2 * j]     = s * e0;
      }
    }
    const int ko = (1 << k) - 2;
    #pragma unroll
    for (int j = 0; j < (1 << k); ++j) A[ko + j] += U[j];
  }
}

// grid 64 x block 64 (one wave). Each block redundantly computes the
// batch-independent signature sig[126], then lane l writes row blk*64+l:
// out[row, d] = x[row]^level(d) * sig[d].
__global__ __launch_bounds__(64, 1)
void Invert_sig_kernel(const float* __restrict__ x,
                       const float* __restrict__ W,
                       float* __restrict__ out) {
  const int lane = threadIdx.x;
  const int row  = blockIdx.x * 64 + lane;

  // ---- prefetch: all global loads issued up-front, independent, so the
  // ~200-900 cyc memory latency is paid once, not 8x serially. ----
  const float xr = x[row];                  // consumed only in phase 3
  float w0[8], w1[8];
  {
    const int t0 = lane * 8;                // increments t0..t0+7 (t0 <= 504)
    #pragma unroll
    for (int s = 0; s < 8; ++s) {
      const int t = t0 + s;
      const bool valid = (t < NINC);        // only lane 63, s==7 is padding
      w0[s] = valid ? W[t + 1] : 0.0f;      // dx[c] = W[c*512 + t + 1]
      w1[s] = valid ? W[NSTEPS + t + 1] : 0.0f;
    }
  }

  float A[SIGDIM];

  // ---- phase 1: fold the lane's 8 consecutive increments ----
  exp_levels(A, w0[0], w1[0]);
  #pragma unroll 1
  for (int s = 1; s < 8; ++s) mul_exp(A, w0[s], w1[s]);  // exp(0)=identity pad ok

  // ---- phase 2: tree-reduce Chen product across 64 lanes (associative) ----
  // C_k = A_k + B_k + sum_{i=1}^{k-1} A_i (x) B_{k-i};  B = partner (higher t).
  // B levels 1..5 materialized (Bv[62]); level-6 B fetched in batches of 16
  // shfls (issue all, single wait, then consume) -> no per-element
  // shfl->use->shfl latency chain, and only +16 registers live.
  // Lockstep safety: every lane processes chunk c's shfls before any lane
  // overwrites its own A[62+16c..] (identical straight-line code per wave).
  #pragma unroll 1
  for (int r = 0; r < 6; ++r) {
    const int bit = 1 << r;
    float Bv[62];
    #pragma unroll
    for (int j = 0; j < 62; ++j) Bv[j] = __shfl_down(A[j], bit, 64);
    // k = 6 in 4 chunks of 16
    #pragma unroll
    for (int c = 0; c < 4; ++c) {
      float b6[16];
      #pragma unroll
      for (int q = 0; q < 16; ++q) b6[q] = __shfl_down(A[62 + 16 * c + q], bit, 64);
      #pragma unroll
      for (int q = 0; q < 16; ++q) {
        const int j = 16 * c + q;
        float v = A[62 + j] + b6[q];
        #pragma unroll
        for (int i = 1; i < 6; ++i)
          v += A[(1 << i) - 2 + (j >> (6 - i))] *
               Bv[(1 << (6 - i)) - 2 + (j & ((1 << (6 - i)) - 1))];
        A[62 + j] = v;
      }
    }
    // k = 5..1 from Bv (descending k => in-place safe; reads only A levels < k)
    #pragma unroll
    for (int k = 5; k >= 1; --k) {
      const int ko = (1 << k) - 2;
      #pragma unroll
      for (int j = 0; j < (1 << k); ++j) {
        float v = A[ko + j] + Bv[ko + j];
        #pragma unroll
        for (int i = 1; i < k; ++i)
          v += A[(1 << i) - 2 + (j >> (k - i))] *
               Bv[(1 << (k - i)) - 2 + (j & ((1 << (k - i)) - 1))];
        A[ko + j] = v;
      }
    }
  }

  __shared__ float sig[SIGDIM];
  if (lane == 0) {
    #pragma unroll
    for (int j = 0; j < SIGDIM; ++j) sig[j] = A[j];
  }
  __syncthreads();

  // ---- phase 3: one output row per lane: out[row,d] = sig[d] * xr^level(d) ----
  float p[7];
  p[1] = xr;
  #pragma unroll
  for (int k = 2; k <= 6; ++k) p[k] = p[k - 1] * xr;

  float* orow = out + row * SIGDIM;   // rows 504 B apart -> 8 B aligned: float2
  #pragma unroll
  for (int d = 0; d < SIGDIM; d += 2) {
    // level boundaries (2,6,14,30,62) are even => pair never straddles levels
    const int k = (d < 2) ? 1 : (d < 6) ? 2 : (d < 14) ? 3
                : (d < 30) ? 4 : (d < 62) ? 5 : 6;
    float2 v;
    v.x = sig[d] * p[k];
    v.y = sig[d + 1] * p[k];
    *reinterpret_cast<float2*>(orow + d) = v;
  }
}

extern "C" void kernel_launch(void* const* d_in, const int* in_sizes, int n_in,
                              void* d_out, int out_size, void* d_ws, size_t ws_size,
                              hipStream_t stream) {
  const float* x = (const float*)d_in[0];  // (4096,1) f32
  const float* W = (const float*)d_in[1];  // (1024,1) f32
  float* out = (float*)d_out;              // (4096,126) f32
  Invert_sig_kernel<<<dim3(64), dim3(64), 0, stream>>>(x, W, out);
}